// Round 1
// baseline (4704.801 us; speedup 1.0000x reference)
//
#include <hip/hip_runtime.h>
#include <stdint.h>

#define B_ 32
#define T_ 512
#define E_ 1024
#define H_ 1024
#define RNN_BLOCKS 64

typedef __attribute__((ext_vector_type(8))) short short8;
typedef __attribute__((ext_vector_type(4))) float floatx4;

__device__ __forceinline__ unsigned short bf16_of(float f) {
    unsigned u = __float_as_uint(f);
    return (unsigned short)((u + 0x8000u) >> 16);   // round-half-up to bf16
}

__device__ __forceinline__ short8 load_bf8(const float* __restrict__ p) {
    const float4* q = (const float4*)p;
    float4 v0 = q[0];
    float4 v1 = q[1];
    short8 r;
    r[0] = (short)bf16_of(v0.x); r[1] = (short)bf16_of(v0.y);
    r[2] = (short)bf16_of(v0.z); r[3] = (short)bf16_of(v0.w);
    r[4] = (short)bf16_of(v1.x); r[5] = (short)bf16_of(v1.y);
    r[6] = (short)bf16_of(v1.z); r[7] = (short)bf16_of(v1.w);
    return r;
}

// ---------------------------------------------------------------------------
// K1: xp[n,h] = sum_e x[n,e] * Wih[h,e] + (bih[h]+bhh[h]),  n = b*T+t
// bf16 MFMA 16x16x32. Block tile 128x128, 4 waves, wave = 32 rows x 128 cols.
// A-frag: lane: m = lane&15, k = (lane>>4)*8 + j   (guide m120, verified)
// B-frag: lane: n = lane&15, k = (lane>>4)*8 + j
// D:      lane: col = lane&15, row = (lane>>4)*4 + reg  (guide m89/m91)
// ---------------------------------------------------------------------------
__global__ __launch_bounds__(256) void k_xp(const float* __restrict__ x,
                                            const float* __restrict__ Wih,
                                            const float* __restrict__ bih,
                                            const float* __restrict__ bhh,
                                            float* __restrict__ out) {
    const int tid  = threadIdx.x;
    const int w    = tid >> 6;
    const int lane = tid & 63;
    const int l15  = lane & 15;
    const int quad = lane >> 4;
    const int rb = blockIdx.x & 127;     // 128 row-blocks of 128 rows
    const int cb = blockIdx.x >> 7;      // 8 col-blocks of 128 cols
    const int row_base = rb * 128 + w * 32;
    const int col_base = cb * 128;

    floatx4 acc[2][8];
#pragma unroll
    for (int i = 0; i < 2; i++)
#pragma unroll
        for (int j = 0; j < 8; j++) acc[i][j] = (floatx4)0.0f;

    for (int k0 = 0; k0 < E_; k0 += 32) {
        const int koff = k0 + quad * 8;
        short8 a[2];
#pragma unroll
        for (int mt = 0; mt < 2; mt++)
            a[mt] = load_bf8(x + (size_t)(row_base + mt * 16 + l15) * E_ + koff);
        short8 b[8];
#pragma unroll
        for (int nt = 0; nt < 8; nt++)
            b[nt] = load_bf8(Wih + (size_t)(col_base + nt * 16 + l15) * E_ + koff);
#pragma unroll
        for (int mt = 0; mt < 2; mt++)
#pragma unroll
            for (int nt = 0; nt < 8; nt++)
                acc[mt][nt] = __builtin_amdgcn_mfma_f32_16x16x32_bf16(
                    a[mt], b[nt], acc[mt][nt], 0, 0, 0);
    }

#pragma unroll
    for (int nt = 0; nt < 8; nt++) {
        const int col = col_base + nt * 16 + l15;
        const float bias = bih[col] + bhh[col];
#pragma unroll
        for (int mt = 0; mt < 2; mt++) {
            const int row = row_base + mt * 16 + quad * 4;
#pragma unroll
            for (int r = 0; r < 4; r++)
                out[(size_t)(row + r) * H_ + col] = acc[mt][nt][r] + bias;
        }
    }
}

// ---------------------------------------------------------------------------
// K2: zero h0 buffer (bf16, 32x1024 -> 16384 uints) and the barrier counter.
// ---------------------------------------------------------------------------
__global__ void k_init(unsigned* __restrict__ hb, unsigned* __restrict__ cnt) {
    const int i = blockIdx.x * blockDim.x + threadIdx.x;
    if (i < (B_ * H_ / 2)) hb[i] = 0u;
    if (i == 0) *cnt = 0u;
}

// ---------------------------------------------------------------------------
// K3: persistent recurrence. 64 blocks x 256 threads. Block owns W_hh rows
// [j0, j0+16) as bf16 B-fragments in registers (8 chunks x 16B/lane = 32 VGPR).
// Per step: D[32 batches x 16 cols] = h_{t-1}[32,1024] @ Wslice^T, K split
// over the 4 waves, partials reduced in LDS, tanh, h written bf16 to ping-pong
// exchange buffer, fp32 to out (in-place over xp). Grid barrier: monotone
// counter, agent-scope fences for cross-XCD visibility.
// ---------------------------------------------------------------------------
__global__ __launch_bounds__(256) void k_rnn(const float* __restrict__ Whh,
                                             float* __restrict__ out,
                                             unsigned* __restrict__ hbu,
                                             unsigned* __restrict__ cnt) {
    const int tid  = threadIdx.x;
    const int w    = tid >> 6;
    const int lane = tid & 63;
    const int l15  = lane & 15;
    const int quad = lane >> 4;
    const int j0   = blockIdx.x * 16;

    __shared__ float red[4][32][16];

    // Load this wave's 8 W-fragments (k in [w*256, w*256+256)) into registers.
    short8 wreg[8];
#pragma unroll
    for (int c = 0; c < 8; c++) {
        const int kc = w * 8 + c;
        wreg[c] = load_bf8(Whh + (size_t)(j0 + l15) * H_ + kc * 32 + quad * 8);
    }

    unsigned short* hb = (unsigned short*)hbu;
    const int eb = tid >> 3;      // epilogue batch 0..31
    const int jp = tid & 7;       // epilogue j-pair 0..7

#pragma unroll 1
    for (int t = 0; t < T_; t++) {
        const unsigned short* cur = hb + (size_t)(t & 1) * (B_ * H_);
        unsigned short*       nxt = hb + (size_t)((t + 1) & 1) * (B_ * H_);

        // prefetch xp for this step (independent of h)
        float2 xv = *(const float2*)(out + ((size_t)eb * T_ + t) * H_ + j0 + jp * 2);

        floatx4 acc[2];
        acc[0] = (floatx4)0.0f;
        acc[1] = (floatx4)0.0f;
#pragma unroll
        for (int c = 0; c < 8; c++) {
            const int k = (w * 8 + c) * 32 + quad * 8;
#pragma unroll
            for (int mt = 0; mt < 2; mt++) {
                short8 ah = *(const short8*)(cur + (size_t)(mt * 16 + l15) * H_ + k);
                acc[mt] = __builtin_amdgcn_mfma_f32_16x16x32_bf16(ah, wreg[c],
                                                                  acc[mt], 0, 0, 0);
            }
        }

        // partial sums -> LDS
#pragma unroll
        for (int mt = 0; mt < 2; mt++)
#pragma unroll
            for (int r = 0; r < 4; r++)
                red[w][mt * 16 + quad * 4 + r][l15] = acc[mt][r];
        __syncthreads();

        // reduce 4 waves, add xp, tanh, write out (fp32) + h (bf16)
        {
            const int j = jp * 2;
            float y0 = red[0][eb][j]     + red[1][eb][j]     + red[2][eb][j]     + red[3][eb][j];
            float y1 = red[0][eb][j + 1] + red[1][eb][j + 1] + red[2][eb][j + 1] + red[3][eb][j + 1];
            const float p0 = xv.x + y0;
            const float p1 = xv.y + y1;
            const float h0 = 1.0f - 2.0f / (__expf(2.0f * p0) + 1.0f);
            const float h1 = 1.0f - 2.0f / (__expf(2.0f * p1) + 1.0f);
            *(float2*)(out + ((size_t)eb * T_ + t) * H_ + j0 + j) = make_float2(h0, h1);
            const unsigned hp = (unsigned)bf16_of(h0) | ((unsigned)bf16_of(h1) << 16);
            *(unsigned*)(nxt + (size_t)eb * H_ + j0 + j) = hp;
        }

        __syncthreads();   // red consumed; also drains stores before fence

        if (t != T_ - 1) {
            if (tid == 0) {
                __threadfence();  // release: write back dirty L2 (cross-XCD)
                __hip_atomic_fetch_add(cnt, 1u, __ATOMIC_RELEASE,
                                       __HIP_MEMORY_SCOPE_AGENT);
                const unsigned target = (unsigned)(RNN_BLOCKS * (t + 1));
                while (__hip_atomic_load(cnt, __ATOMIC_RELAXED,
                                         __HIP_MEMORY_SCOPE_AGENT) < target) {
                    __builtin_amdgcn_s_sleep(1);
                }
                __threadfence();  // acquire: invalidate stale L1/L2 lines
            }
            __syncthreads();
        }
    }
}

// ---------------------------------------------------------------------------
extern "C" void kernel_launch(void* const* d_in, const int* in_sizes, int n_in,
                              void* d_out, int out_size, void* d_ws, size_t ws_size,
                              hipStream_t stream) {
    const float* x   = (const float*)d_in[0];
    const float* Wih = (const float*)d_in[1];
    const float* Whh = (const float*)d_in[2];
    const float* bih = (const float*)d_in[3];
    const float* bhh = (const float*)d_in[4];
    float* out = (float*)d_out;

    // ws layout: [0,128KB) ping-pong bf16 h buffers; counter at 128KB.
    unsigned* hb  = (unsigned*)d_ws;
    unsigned* cnt = (unsigned*)((char*)d_ws + 2 * B_ * H_ * sizeof(unsigned short));

    k_init<<<64, 256, 0, stream>>>(hb, cnt);
    k_xp<<<128 * 8, 256, 0, stream>>>(x, Wih, bih, bhh, out);
    k_rnn<<<RNN_BLOCKS, 256, 0, stream>>>(Whh, out, hb, cnt);
}

// Round 2
// 2640.130 us; speedup vs baseline: 1.7820x; 1.7820x over previous
//
#include <hip/hip_runtime.h>
#include <stdint.h>

#define B_ 32
#define T_ 512
#define E_ 1024
#define H_ 1024
#define NWAVE 64   // k_rnn: 64 blocks x 1 wave; wave j owns h-cols [16j,16j+16)

typedef __attribute__((ext_vector_type(8))) short short8;
typedef __attribute__((ext_vector_type(4))) float floatx4;

__device__ __forceinline__ unsigned short bf16_of(float f) {
    unsigned u = __float_as_uint(f);
    return (unsigned short)((u + 0x8000u) >> 16);   // round-half-up to bf16
}

__device__ __forceinline__ short8 load_bf8(const float* __restrict__ p) {
    const float4* q = (const float4*)p;
    float4 v0 = q[0];
    float4 v1 = q[1];
    short8 r;
    r[0] = (short)bf16_of(v0.x); r[1] = (short)bf16_of(v0.y);
    r[2] = (short)bf16_of(v0.z); r[3] = (short)bf16_of(v0.w);
    r[4] = (short)bf16_of(v1.x); r[5] = (short)bf16_of(v1.y);
    r[6] = (short)bf16_of(v1.z); r[7] = (short)bf16_of(v1.w);
    return r;
}

// ---------------------------------------------------------------------------
// K1: xp[n,h] = sum_e x[n,e] * Wih[h,e] + (bih[h]+bhh[h]),  n = b*T+t
// (unchanged from round 1 — isolate the k_rnn experiment)
// ---------------------------------------------------------------------------
__global__ __launch_bounds__(256) void k_xp(const float* __restrict__ x,
                                            const float* __restrict__ Wih,
                                            const float* __restrict__ bih,
                                            const float* __restrict__ bhh,
                                            float* __restrict__ out) {
    const int tid  = threadIdx.x;
    const int w    = tid >> 6;
    const int lane = tid & 63;
    const int l15  = lane & 15;
    const int quad = lane >> 4;
    const int rb = blockIdx.x & 127;
    const int cb = blockIdx.x >> 7;
    const int row_base = rb * 128 + w * 32;
    const int col_base = cb * 128;

    floatx4 acc[2][8];
#pragma unroll
    for (int i = 0; i < 2; i++)
#pragma unroll
        for (int j = 0; j < 8; j++) acc[i][j] = (floatx4)0.0f;

    for (int k0 = 0; k0 < E_; k0 += 32) {
        const int koff = k0 + quad * 8;
        short8 a[2];
#pragma unroll
        for (int mt = 0; mt < 2; mt++)
            a[mt] = load_bf8(x + (size_t)(row_base + mt * 16 + l15) * E_ + koff);
        short8 b[8];
#pragma unroll
        for (int nt = 0; nt < 8; nt++)
            b[nt] = load_bf8(Wih + (size_t)(col_base + nt * 16 + l15) * E_ + koff);
#pragma unroll
        for (int mt = 0; mt < 2; mt++)
#pragma unroll
            for (int nt = 0; nt < 8; nt++)
                acc[mt][nt] = __builtin_amdgcn_mfma_f32_16x16x32_bf16(
                    a[mt], b[nt], acc[mt][nt], 0, 0, 0);
    }

#pragma unroll
    for (int nt = 0; nt < 8; nt++) {
        const int col = col_base + nt * 16 + l15;
        const float bias = bih[col] + bhh[col];
#pragma unroll
        for (int mt = 0; mt < 2; mt++) {
            const int row = row_base + mt * 16 + quad * 4;
#pragma unroll
            for (int r = 0; r < 4; r++)
                out[(size_t)(row + r) * H_ + col] = acc[mt][nt][r] + bias;
        }
    }
}

// ---------------------------------------------------------------------------
// K2: zero ws: h ping-pong (2 x 32x1024 bf16 = 32768 u32) + 64 flags (x16 pad
// = 1024 u32). Total 33792 u32 -> 132 blocks x 256.
// ---------------------------------------------------------------------------
__global__ void k_init(unsigned* __restrict__ ws) {
    const int i = blockIdx.x * blockDim.x + threadIdx.x;
    if (i < 33792) ws[i] = 0u;
}

// ---------------------------------------------------------------------------
// K3 v2: wave-dataflow recurrence. 64 blocks x 64 threads (1 wave). Wave j
// owns cols [16j,16j+16) with the FULL-K W_hh slice in 128 VGPRs (32 x short8
// B-fragments). Per step: poll 64 per-wave flags (parallel, one lane each,
// no atomic RMW), acquire fence (buffer_inv, no wbl2), vectorized h loads,
// 64 MFMAs, in-register tanh, write-through agent atomic h stores (packed
// 4B via shfl_xor), vmcnt(0), one relaxed flag store. No __syncthreads,
// no counter, no L2 writeback.
// Skew safety: wave at step s+2 writes buf[(s+1)&1]; it can only get there
// after seeing all flags >= s+2, i.e. every wave finished step s+1 (whose
// reads of buf[(s+1)&1] precede its flag store). Ping-pong is sufficient.
// ---------------------------------------------------------------------------
__global__ __launch_bounds__(64, 1) void k_rnn(const float* __restrict__ Whh,
                                               float* __restrict__ out,
                                               unsigned* __restrict__ ws) {
    const int lane = threadIdx.x;     // 0..63
    const int l15  = lane & 15;
    const int quad = lane >> 4;
    const int wid  = blockIdx.x;      // 0..63
    const int j0   = wid * 16;

    unsigned short* hb    = (unsigned short*)ws;          // 2 x B_*H_ bf16
    unsigned*       flags = ws + 32768;                   // 64 flags, 64B stride

    // Full-K W_hh B-fragments: wreg[c] covers k in [32c + quad*8, +8), col j0+l15.
    short8 wreg[32];
#pragma unroll
    for (int c = 0; c < 32; c++)
        wreg[c] = load_bf8(Whh + (size_t)(j0 + l15) * H_ + c * 32 + quad * 8);

#pragma unroll 1
    for (int t = 0; t < T_; t++) {
        const unsigned short* cur = hb + (size_t)(t & 1) * (B_ * H_);
        unsigned short*       nxt = hb + (size_t)((t + 1) & 1) * (B_ * H_);

        // xp prefetch (independent of h): batch = mt*16+quad*4+r, col = j0+l15
        float xv[2][4];
#pragma unroll
        for (int mt = 0; mt < 2; mt++)
#pragma unroll
            for (int r = 0; r < 4; r++) {
                const int b = mt * 16 + quad * 4 + r;
                xv[mt][r] = out[((size_t)b * T_ + t) * H_ + j0 + l15];
            }

        if (t > 0) {
            const unsigned tv = (unsigned)t;
            while (true) {
                unsigned v = __hip_atomic_load(&flags[lane * 16], __ATOMIC_RELAXED,
                                               __HIP_MEMORY_SCOPE_AGENT);
                if (__ballot(v < tv) == 0ull) break;
            }
            __builtin_amdgcn_fence(__ATOMIC_ACQUIRE, "agent");  // inv stale L1/L2
        }

        floatx4 acc[2];
        acc[0] = (floatx4)0.0f;
        acc[1] = (floatx4)0.0f;
#pragma unroll
        for (int c = 0; c < 32; c++) {
#pragma unroll
            for (int mt = 0; mt < 2; mt++) {
                short8 ah = *(const short8*)(cur + (size_t)(mt * 16 + l15) * H_ +
                                             c * 32 + quad * 8);
                acc[mt] = __builtin_amdgcn_mfma_f32_16x16x32_bf16(ah, wreg[c],
                                                                  acc[mt], 0, 0, 0);
            }
        }

        // Epilogue: D layout col=l15, batch=mt*16+quad*4+r. tanh in-register.
#pragma unroll
        for (int mt = 0; mt < 2; mt++) {
#pragma unroll
            for (int r = 0; r < 4; r++) {
                const int b = mt * 16 + quad * 4 + r;
                const float p = xv[mt][r] + acc[mt][r];
                const float h = 1.0f - 2.0f / (__expf(2.0f * p) + 1.0f);
                out[((size_t)b * T_ + t) * H_ + j0 + l15] = h;
                const unsigned short hu = bf16_of(h);
                const unsigned short pu =
                    (unsigned short)__shfl_xor((int)hu, 1, 64);
                if ((l15 & 1) == 0) {   // even lane packs cols (l15, l15+1)
                    const unsigned packed = (unsigned)hu | ((unsigned)pu << 16);
                    __hip_atomic_store(
                        (unsigned*)(nxt + (size_t)b * H_ + j0 + l15), packed,
                        __ATOMIC_RELAXED, __HIP_MEMORY_SCOPE_AGENT);
                }
            }
        }

        // All write-through h stores acked at the coherence point, then flag.
        asm volatile("s_waitcnt vmcnt(0)" ::: "memory");
        if (lane == 0)
            __hip_atomic_store(&flags[wid * 16], (unsigned)(t + 1),
                               __ATOMIC_RELAXED, __HIP_MEMORY_SCOPE_AGENT);
    }
}

// ---------------------------------------------------------------------------
extern "C" void kernel_launch(void* const* d_in, const int* in_sizes, int n_in,
                              void* d_out, int out_size, void* d_ws, size_t ws_size,
                              hipStream_t stream) {
    const float* x   = (const float*)d_in[0];
    const float* Wih = (const float*)d_in[1];
    const float* Whh = (const float*)d_in[2];
    const float* bih = (const float*)d_in[3];
    const float* bhh = (const float*)d_in[4];
    float* out = (float*)d_out;
    unsigned* ws = (unsigned*)d_ws;

    k_init<<<132, 256, 0, stream>>>(ws);
    k_xp<<<128 * 8, 256, 0, stream>>>(x, Wih, bih, bhh, out);
    k_rnn<<<NWAVE, 64, 0, stream>>>(Whh, out, ws);
}